// Round 14
// baseline (518.339 us; speedup 1.0000x reference)
//
#include <hip/hip_runtime.h>
#include <hip/hip_bf16.h>
#include <stdint.h>

#define HID 1024
#define INTER_ 4096
#define NE 8
#define NTOK 8192
#define NPAIR (NTOK * 2)
#define MAXT 72   // sum ceil(cnt_e/256) <= 16384/256 + 8

using f32x4 = __attribute__((ext_vector_type(4))) float;
using bf16x8 = __attribute__((ext_vector_type(8))) __bf16;
using ushort8v = __attribute__((ext_vector_type(8))) unsigned short;

__device__ __forceinline__ unsigned short f2b(float f) {
  unsigned int u = __float_as_uint(f);
  u += 0x7fffu + ((u >> 16) & 1u);
  return (unsigned short)(u >> 16);
}
__device__ __forceinline__ float b2f(unsigned short u) {
  return __uint_as_float((unsigned int)u << 16);
}

// branch-free gelu: A&S 7.1.26 erf (abs err 1.5e-7)
__device__ __forceinline__ float gelu_f(float v) {
  float z = fabsf(v) * 0.70710678118654752f;
  float t = __builtin_amdgcn_rcpf(1.f + 0.3275911f * z);
  float p = t * (0.254829592f +
            t * (-0.284496736f +
            t * (1.421413741f +
            t * (-1.453152027f + t * 1.061405429f))));
  float er = 1.f - p * __expf(-z * z);
  er = copysignf(er, v);
  return 0.5f * v * (1.f + er);
}

#define GLD_LDS(gp, lp)                                                        \
  __builtin_amdgcn_global_load_lds(                                            \
      (const __attribute__((address_space(1))) unsigned int*)(const void*)(gp),\
      (__attribute__((address_space(3))) unsigned int*)(void*)(lp), 16, 0, 0)

#define WAITV(N) asm volatile("s_waitcnt vmcnt(" #N ")" ::: "memory")

// ---------------- gating: one wave per token, fp32; also emits xb ----------------
__global__ __launch_bounds__(256) void gate_kernel(
    const float* __restrict__ x, const float* __restrict__ gw,
    int* __restrict__ topi, float* __restrict__ topw,
    unsigned short* __restrict__ xb)
{
  int gwave = (blockIdx.x * 256 + threadIdx.x) >> 6;
  int lane = threadIdx.x & 63;
  if (gwave >= NTOK) return;
  const float* xr = x + (size_t)gwave * HID;
  unsigned short* xo = xb + (size_t)gwave * HID;
  float acc[NE];
#pragma unroll
  for (int e = 0; e < NE; ++e) acc[e] = 0.f;
#pragma unroll
  for (int q = 0; q < 4; ++q) {
    float4 v = *reinterpret_cast<const float4*>(xr + q * 256 + lane * 4);
    ushort4 uv;
    uv.x = f2b(v.x); uv.y = f2b(v.y); uv.z = f2b(v.z); uv.w = f2b(v.w);
    *reinterpret_cast<ushort4*>(xo + q * 256 + lane * 4) = uv;
#pragma unroll
    for (int e = 0; e < NE; ++e) {
      float4 wv = *reinterpret_cast<const float4*>(gw + e * HID + q * 256 + lane * 4);
      acc[e] += v.x * wv.x + v.y * wv.y + v.z * wv.z + v.w * wv.w;
    }
  }
#pragma unroll
  for (int e = 0; e < NE; ++e) {
#pragma unroll
    for (int off = 32; off > 0; off >>= 1) acc[e] += __shfl_xor(acc[e], off);
  }
  if (lane == 0) {
    float v0 = -1e30f; int i0 = 0;
#pragma unroll
    for (int e = 0; e < NE; ++e) if (acc[e] > v0) { v0 = acc[e]; i0 = e; }
    float v1 = -1e30f; int i1 = 0;
#pragma unroll
    for (int e = 0; e < NE; ++e) if (e != i0 && acc[e] > v1) { v1 = acc[e]; i1 = e; }
    float e1 = __expf(v1 - v0);
    float s = 1.f + e1;
    topi[gwave * 2] = i0; topi[gwave * 2 + 1] = i1;
    topw[gwave * 2] = 1.f / s; topw[gwave * 2 + 1] = e1 / s;
  }
}

// ---------- deterministic ballot-rank scatter: hist -> scan -> scatter ----------
__global__ __launch_bounds__(256) void hist_kernel(const int* __restrict__ topi,
                                                   int* __restrict__ bcnt)
{
  int tid = threadIdx.x, blk = blockIdx.x;
  int t = blk * 256 + tid;
  int e0 = topi[t * 2], e1 = topi[t * 2 + 1];
  int w = tid >> 6, lane = tid & 63;
  __shared__ int wcnt[4][NE];
#pragma unroll
  for (int e = 0; e < NE; ++e) {
    unsigned long long m0 = __ballot(e0 == e);
    unsigned long long m1 = __ballot(e1 == e);
    if (lane == 0) wcnt[w][e] = __popcll(m0) + __popcll(m1);
  }
  __syncthreads();
  if (tid < NE) {
    int s = 0;
#pragma unroll
    for (int w2 = 0; w2 < 4; ++w2) s += wcnt[w2][tid];
    bcnt[blk * NE + tid] = s;
  }
}

__global__ void scan2_kernel(const int* __restrict__ bcnt, int* __restrict__ offs,
                             int* __restrict__ tile_e, int* __restrict__ tile_m,
                             int* __restrict__ ntile, int* __restrict__ gbase)
{
  __shared__ int cnts[NE];
  __shared__ int soffs[NE];
  int tid = threadIdx.x;
  if (tid < NE) {
    int s = 0;
#pragma unroll
    for (int b = 0; b < 32; ++b) s += bcnt[b * NE + tid];
    cnts[tid] = s;
  }
  __syncthreads();
  if (tid == 0) {
    int o = 0, tt = 0;
    for (int e = 0; e < NE; ++e) {
      offs[e] = o; soffs[e] = o;
      int c = cnts[e];
      for (int m = 0; m < c; m += 256) { tile_e[tt] = e; tile_m[tt] = m; ++tt; }
      o += c;
    }
    offs[NE] = o;
    *ntile = tt;
  }
  __syncthreads();
  if (tid < 32 * NE) {
    int b = tid >> 3, e = tid & 7;
    int g = soffs[e];
    for (int b2 = 0; b2 < b; ++b2) g += bcnt[b2 * NE + e];
    gbase[b * NE + e] = g;
  }
}

__global__ __launch_bounds__(256) void scatter2_kernel(
    const int* __restrict__ topi, const float* __restrict__ topw,
    const int* __restrict__ gbase,
    int* __restrict__ toklist, float* __restrict__ wlist)
{
  int tid = threadIdx.x, blk = blockIdx.x;
  int t = blk * 256 + tid;
  int e0 = topi[t * 2], e1 = topi[t * 2 + 1];
  float w0 = topw[t * 2], w1 = topw[t * 2 + 1];
  int w = tid >> 6, lane = tid & 63;
  unsigned long long lt = (1ull << lane) - 1ull;
  unsigned long long le = lt | (1ull << lane);
  __shared__ int wcnt[4][NE];
  __shared__ int wbase[4][NE];
  int r0 = 0, r1 = 0;
#pragma unroll
  for (int e = 0; e < NE; ++e) {
    unsigned long long m0 = __ballot(e0 == e);
    unsigned long long m1 = __ballot(e1 == e);
    if (lane == 0) wcnt[w][e] = __popcll(m0) + __popcll(m1);
    if (e0 == e) r0 = __popcll(m0 & lt) + __popcll(m1 & lt);
    if (e1 == e) r1 = __popcll(m0 & le) + __popcll(m1 & lt);
  }
  __syncthreads();
  if (tid < 4 * NE) {
    int w2 = tid >> 3, e = tid & 7;
    int b = gbase[blk * NE + e];
    for (int w3 = 0; w3 < w2; ++w3) b += wcnt[w3][e];
    wbase[w2][e] = b;
  }
  __syncthreads();
  int P0 = wbase[w][e0] + r0;
  int P1 = wbase[w][e1] + r1;
  toklist[P0] = t; wlist[P0] = w0;
  toklist[P1] = t; wlist[P1] = w1;
}

// ---------------- fp32 -> bf16 convert, W1 and W2 in one launch ----------------
__global__ __launch_bounds__(256) void cvtw_kernel(
    const float* __restrict__ W1, const float* __restrict__ W2,
    unsigned short* __restrict__ w1b, unsigned short* __restrict__ w2b, int n8)
{
  int half = gridDim.x >> 1;
  const float* src = (blockIdx.x < half) ? W1 : W2;
  unsigned short* dst = (blockIdx.x < half) ? w1b : w2b;
  int b0 = (blockIdx.x < half) ? blockIdx.x : blockIdx.x - half;
  int stride = half * 256;
  for (int i = b0 * 256 + threadIdx.x; i < n8; i += stride) {
    const float4* s = reinterpret_cast<const float4*>(src) + (size_t)i * 2;
    float4 a = s[0], b = s[1];
    ushort8v u;
    u[0] = f2b(a.x); u[1] = f2b(a.y); u[2] = f2b(a.z); u[3] = f2b(a.w);
    u[4] = f2b(b.x); u[5] = f2b(b.y); u[6] = f2b(b.z); u[7] = f2b(b.w);
    reinterpret_cast<ushort8v*>(dst)[i] = u;
  }
}

// ====== GEMM kernels (R13-proven): 256M x 128N tile, BK=32, 3-slot LDS ring
// (72 KB -> 2 blocks/CU), 8 waves (4M x 2N), wave tile 64x64. Pipeline:
//   { stage(s+2); WAITV(3) [s+1 landed]; s_barrier; MFMA(s) [frags in regs];
//     ds_read frags(s+1) }

// GEMM1: h = gelu(x @ W1[e]^T + b1[e]) -> bf16
__global__ __launch_bounds__(512, 4) void gemm1_kernel(
    const unsigned short* __restrict__ xb, const unsigned short* __restrict__ w1b,
    const float* __restrict__ b1,
    const int* __restrict__ toklist, const int* __restrict__ offs,
    const int* __restrict__ tile_e, const int* __restrict__ tile_m,
    const int* __restrict__ ntile,
    unsigned short* __restrict__ hb)
{
  const int h = blockIdx.x;            // 0..2303 = 8 xcd * (9 tiles * 32 n)
  const int xcd = h & 7;
  const int j = h >> 3;                // 0..287
  const int t = 9 * xcd + j % 9;
  const int n0 = (j / 9) * 128;        // 0..31 n-tiles
  if (t >= *ntile) return;
  const int e = tile_e[t];
  const int m0 = tile_m[t];
  const int base = offs[e];
  const int cnt = offs[e + 1] - base;

  __shared__ __align__(16) unsigned short As[3][256 * 32];  // 48 KB
  __shared__ __align__(16) unsigned short Bs[3][128 * 32];  // 24 KB

  const int tid = threadIdx.x;         // 0..511
  const int lane = tid & 63;
  const int w = tid >> 6;
  const int wr = w >> 1, wc = w & 1;   // 4M x 2N waves; per-wave out 64x64

  const int r0 = tid >> 2;             // 0..127
  const int sl = tid & 3;
  const int scg = sl ^ ((r0 >> 1) & 3);
  const unsigned short* gA[2];
  const unsigned short* gB;
#pragma unroll
  for (int g = 0; g < 2; ++g) {
    int row = g * 128 + r0;
    int mrow = m0 + row; if (mrow >= cnt) mrow = cnt - 1;
    int tk = toklist[base + mrow];
    gA[g] = xb + (size_t)tk * HID + scg * 8;
  }
  gB = w1b + ((size_t)e * INTER_ + n0 + r0) * HID + scg * 8;

  int raq[4], rbq[4];
#pragma unroll
  for (int i = 0; i < 4; ++i) {
    int rA = wr * 64 + i * 16 + (lane & 15);
    raq[i] = rA * 32 + (((lane >> 4) ^ ((rA >> 1) & 3)) * 8);
    int rB = wc * 64 + i * 16 + (lane & 15);
    rbq[i] = rB * 32 + (((lane >> 4) ^ ((rB >> 1) & 3)) * 8);
  }

  f32x4 acc[4][4];
#pragma unroll
  for (int i = 0; i < 4; ++i)
#pragma unroll
    for (int j2 = 0; j2 < 4; ++j2) acc[i][j2] = (f32x4){0.f, 0.f, 0.f, 0.f};

  bf16x8 afr[4], bfr[4];

  auto stage = [&](int slot, int s) {
    const int kof = s * 32;
    GLD_LDS(gA[0] + kof, &As[slot][tid * 8]);
    GLD_LDS(gA[1] + kof, &As[slot][4096 + tid * 8]);
    GLD_LDS(gB + kof,    &Bs[slot][tid * 8]);
  };
  auto load_frags = [&](int slot) {
    const unsigned short* Ab = &As[slot][0];
    const unsigned short* Bb = &Bs[slot][0];
#pragma unroll
    for (int j2 = 0; j2 < 4; ++j2) bfr[j2] = *reinterpret_cast<const bf16x8*>(Bb + rbq[j2]);
#pragma unroll
    for (int i = 0; i < 4; ++i) afr[i] = *reinterpret_cast<const bf16x8*>(Ab + raq[i]);
  };
  auto mfma_step = [&]() {
#pragma unroll
    for (int i = 0; i < 4; ++i)
#pragma unroll
      for (int j2 = 0; j2 < 4; ++j2)
        acc[i][j2] = __builtin_amdgcn_mfma_f32_16x16x32_bf16(afr[i], bfr[j2], acc[i][j2], 0, 0, 0);
  };

  const int NS = HID / 32;   // 32
  stage(0, 0); stage(1, 1);
  WAITV(3);
  __builtin_amdgcn_s_barrier();
  load_frags(0);
#pragma unroll 3
  for (int s = 0; s < NS - 2; ++s) {
    stage((s + 2) % 3, s + 2);
    WAITV(3);
    __builtin_amdgcn_s_barrier();
    mfma_step();
    load_frags((s + 1) % 3);
  }
  WAITV(0);
  __builtin_amdgcn_s_barrier();
  mfma_step();
  load_frags((NS - 1) % 3);
  mfma_step();

  float bias[4];
  const int colb = n0 + wc * 64 + (lane & 15);
#pragma unroll
  for (int j2 = 0; j2 < 4; ++j2) bias[j2] = b1[(size_t)e * INTER_ + colb + j2 * 16];
#pragma unroll
  for (int i = 0; i < 4; ++i) {
    int mbase = m0 + wr * 64 + i * 16 + (lane >> 4) * 4;
#pragma unroll
    for (int r = 0; r < 4; ++r) {
      int m = mbase + r;
      if (m < cnt) {
        unsigned short* hrow = hb + (size_t)(base + m) * INTER_ + colb;
#pragma unroll
        for (int j2 = 0; j2 < 4; ++j2)
          hrow[j2 * 16] = f2b(gelu_f(acc[i][j2][r] + bias[j2]));
      }
    }
  }
}

// GEMM2: out += w * (h @ W2[e]^T + b2[e]) — split-K=2, FUSED epilogue:
// fp32 atomicAdd directly to out (bias applied by split 0 only). No part
// buffer, no combine kernel.
__global__ __launch_bounds__(512, 4) void gemm2_kernel(
    const unsigned short* __restrict__ hb, const unsigned short* __restrict__ w2b,
    const float* __restrict__ b2,
    const int* __restrict__ toklist, const float* __restrict__ wlist,
    const int* __restrict__ offs,
    const int* __restrict__ tile_e, const int* __restrict__ tile_m,
    const int* __restrict__ ntile,
    float* __restrict__ out)
{
  const int h = blockIdx.x;
  const int xcd = h & 7;
  const int j = h >> 3;            // 0..71
  const int t = 9 * xcd + j % 9;
  const int nb = j / 9;            // 0..7
  if (t >= *ntile) return;
  const int e = tile_e[t];
  const int m0 = tile_m[t];
  const int base = offs[e];
  const int cnt = offs[e + 1] - base;
  const int n0 = nb * 128;
  const int kbase = blockIdx.z * (INTER_ / 2);

  __shared__ __align__(16) unsigned short As[3][256 * 32];
  __shared__ __align__(16) unsigned short Bs[3][128 * 32];

  const int tid = threadIdx.x;
  const int lane = tid & 63;
  const int w = tid >> 6;
  const int wr = w >> 1, wc = w & 1;

  const int r0 = tid >> 2;
  const int sl = tid & 3;
  const int scg = sl ^ ((r0 >> 1) & 3);
  const unsigned short* gA[2];
  const unsigned short* gB;
#pragma unroll
  for (int g = 0; g < 2; ++g) {
    int row = g * 128 + r0;
    int mrow = m0 + row; if (mrow >= cnt) mrow = cnt - 1;
    gA[g] = hb + (size_t)(base + mrow) * INTER_ + kbase + scg * 8;
  }
  gB = w2b + ((size_t)e * HID + n0 + r0) * INTER_ + kbase + scg * 8;

  int raq[4], rbq[4];
#pragma unroll
  for (int i = 0; i < 4; ++i) {
    int rA = wr * 64 + i * 16 + (lane & 15);
    raq[i] = rA * 32 + (((lane >> 4) ^ ((rA >> 1) & 3)) * 8);
    int rB = wc * 64 + i * 16 + (lane & 15);
    rbq[i] = rB * 32 + (((lane >> 4) ^ ((rB >> 1) & 3)) * 8);
  }

  f32x4 acc[4][4];
#pragma unroll
  for (int i = 0; i < 4; ++i)
#pragma unroll
    for (int j2 = 0; j2 < 4; ++j2) acc[i][j2] = (f32x4){0.f, 0.f, 0.f, 0.f};

  bf16x8 afr[4], bfr[4];

  auto stage = [&](int slot, int s) {
    const int kof = s * 32;
    GLD_LDS(gA[0] + kof, &As[slot][tid * 8]);
    GLD_LDS(gA[1] + kof, &As[slot][4096 + tid * 8]);
    GLD_LDS(gB + kof,    &Bs[slot][tid * 8]);
  };
  auto load_frags = [&](int slot) {
    const unsigned short* Ab = &As[slot][0];
    const unsigned short* Bb = &Bs[slot][0];
#pragma unroll
    for (int j2 = 0; j2 < 4; ++j2) bfr[j2] = *reinterpret_cast<const bf16x8*>(Bb + rbq[j2]);
#pragma unroll
    for (int i = 0; i < 4; ++i) afr[i] = *reinterpret_cast<const bf16x8*>(Ab + raq[i]);
  };
  auto mfma_step = [&]() {
#pragma unroll
    for (int i = 0; i < 4; ++i)
#pragma unroll
      for (int j2 = 0; j2 < 4; ++j2)
        acc[i][j2] = __builtin_amdgcn_mfma_f32_16x16x32_bf16(afr[i], bfr[j2], acc[i][j2], 0, 0, 0);
  };

  const int NS = (INTER_ / 2) / 32;   // 64
  stage(0, 0); stage(1, 1);
  WAITV(3);
  __builtin_amdgcn_s_barrier();
  load_frags(0);
#pragma unroll 3
  for (int s = 0; s < NS - 2; ++s) {
    stage((s + 2) % 3, s + 2);
    WAITV(3);
    __builtin_amdgcn_s_barrier();
    mfma_step();
    load_frags((s + 1) % 3);
  }
  WAITV(0);
  __builtin_amdgcn_s_barrier();
  mfma_step();
  load_frags((NS - 1) % 3);
  mfma_step();

  const int colb = n0 + wc * 64 + (lane & 15);
  const float bscale = (blockIdx.z == 0) ? 1.f : 0.f;
  float bias[4];
#pragma unroll
  for (int j2 = 0; j2 < 4; ++j2) bias[j2] = bscale * b2[(size_t)e * HID + colb + j2 * 16];
#pragma unroll
  for (int i = 0; i < 4; ++i) {
    int mbase = m0 + wr * 64 + i * 16 + (lane >> 4) * 4;
#pragma unroll
    for (int r = 0; r < 4; ++r) {
      int m = mbase + r;
      if (m < cnt) {
        int tk = toklist[base + m];
        float wt = wlist[base + m];
        float* orow = out + (size_t)tk * HID + colb;
#pragma unroll
        for (int j2 = 0; j2 < 4; ++j2)
          atomicAdd(&orow[j2 * 16], wt * (acc[i][j2][r] + bias[j2]));
      }
    }
  }
}

extern "C" void kernel_launch(void* const* d_in, const int* in_sizes, int n_in,
                              void* d_out, int out_size, void* d_ws, size_t ws_size,
                              hipStream_t stream) {
  const float* x  = (const float*)d_in[0];
  const float* gw = (const float*)d_in[1];
  const float* W1 = (const float*)d_in[2];
  const float* b1 = (const float*)d_in[3];
  const float* W2 = (const float*)d_in[4];
  const float* b2 = (const float*)d_in[5];
  float* out = (float*)d_out;

  char* ws = (char*)d_ws;
  size_t off = 0;
  auto alloc = [&](size_t bytes) -> void* {
    void* p = ws + off;
    off += (bytes + 255) & ~(size_t)255;
    return p;
  };
  unsigned short* hb   = (unsigned short*)alloc((size_t)NPAIR * INTER_ * 2);     // 134.2 MB
  unsigned short* xb   = (unsigned short*)alloc((size_t)NTOK * HID * 2);         //  16.8 MB
  unsigned short* w1b  = (unsigned short*)alloc((size_t)NE * INTER_ * HID * 2);  //  67.1 MB
  unsigned short* w2b  = (unsigned short*)alloc((size_t)NE * HID * INTER_ * 2);  //  67.1 MB
  int*   toklist = (int*)alloc(NPAIR * 4);
  float* wlist   = (float*)alloc(NPAIR * 4);
  int*   topi    = (int*)alloc(NTOK * 2 * 4);
  float* topw    = (float*)alloc(NTOK * 2 * 4);
  int*   bcnt    = (int*)alloc(32 * NE * 4);
  int*   gbase   = (int*)alloc(32 * NE * 4);
  int*   offs    = (int*)alloc(64);
  int*   tile_e  = (int*)alloc(MAXT * 4);
  int*   tile_m  = (int*)alloc(MAXT * 4);
  int*   ntile   = (int*)alloc(64);

  hipMemsetAsync(out, 0, (size_t)out_size * sizeof(float), stream);

  gate_kernel<<<NTOK / 4, 256, 0, stream>>>(x, gw, topi, topw, xb);
  hist_kernel<<<32, 256, 0, stream>>>(topi, bcnt);
  scan2_kernel<<<1, 256, 0, stream>>>(bcnt, offs, tile_e, tile_m, ntile, gbase);
  scatter2_kernel<<<32, 256, 0, stream>>>(topi, topw, gbase, toklist, wlist);
  cvtw_kernel<<<4096, 256, 0, stream>>>(W1, W2, w1b, w2b, NE * INTER_ * HID / 8);
  gemm1_kernel<<<dim3(8 * 9 * 32), 512, 0, stream>>>(
      xb, w1b, b1, toklist, offs, tile_e, tile_m, ntile, hb);
  gemm2_kernel<<<dim3(8 * MAXT, 1, 2), 512, 0, stream>>>(
      hb, w2b, b2, toklist, wlist, offs, tile_e, tile_m, ntile, out);
}

// Round 15
// 494.738 us; speedup vs baseline: 1.0477x; 1.0477x over previous
//
#include <hip/hip_runtime.h>
#include <hip/hip_bf16.h>
#include <stdint.h>

#define HID 1024
#define INTER_ 4096
#define NE 8
#define NTOK 8192
#define NPAIR (NTOK * 2)
#define MAXT 72   // sum ceil(cnt_e/256) <= 16384/256 + 8

using f32x4 = __attribute__((ext_vector_type(4))) float;
using bf16x8 = __attribute__((ext_vector_type(8))) __bf16;
using ushort8v = __attribute__((ext_vector_type(8))) unsigned short;

__device__ __forceinline__ unsigned short f2b(float f) {
  unsigned int u = __float_as_uint(f);
  u += 0x7fffu + ((u >> 16) & 1u);
  return (unsigned short)(u >> 16);
}
__device__ __forceinline__ float b2f(unsigned short u) {
  return __uint_as_float((unsigned int)u << 16);
}

// branch-free gelu: A&S 7.1.26 erf (abs err 1.5e-7)
__device__ __forceinline__ float gelu_f(float v) {
  float z = fabsf(v) * 0.70710678118654752f;
  float t = __builtin_amdgcn_rcpf(1.f + 0.3275911f * z);
  float p = t * (0.254829592f +
            t * (-0.284496736f +
            t * (1.421413741f +
            t * (-1.453152027f + t * 1.061405429f))));
  float er = 1.f - p * __expf(-z * z);
  er = copysignf(er, v);
  return 0.5f * v * (1.f + er);
}

#define GLD_LDS(gp, lp)                                                        \
  __builtin_amdgcn_global_load_lds(                                            \
      (const __attribute__((address_space(1))) unsigned int*)(const void*)(gp),\
      (__attribute__((address_space(3))) unsigned int*)(void*)(lp), 16, 0, 0)

#define WAITV(N) asm volatile("s_waitcnt vmcnt(" #N ")" ::: "memory")

// ---------------- gating: one wave per token, fp32; also emits xb ----------------
__global__ __launch_bounds__(256) void gate_kernel(
    const float* __restrict__ x, const float* __restrict__ gw,
    int* __restrict__ topi, float* __restrict__ topw,
    unsigned short* __restrict__ xb)
{
  int gwave = (blockIdx.x * 256 + threadIdx.x) >> 6;
  int lane = threadIdx.x & 63;
  if (gwave >= NTOK) return;
  const float* xr = x + (size_t)gwave * HID;
  unsigned short* xo = xb + (size_t)gwave * HID;
  float acc[NE];
#pragma unroll
  for (int e = 0; e < NE; ++e) acc[e] = 0.f;
#pragma unroll
  for (int q = 0; q < 4; ++q) {
    float4 v = *reinterpret_cast<const float4*>(xr + q * 256 + lane * 4);
    ushort4 uv;
    uv.x = f2b(v.x); uv.y = f2b(v.y); uv.z = f2b(v.z); uv.w = f2b(v.w);
    *reinterpret_cast<ushort4*>(xo + q * 256 + lane * 4) = uv;
#pragma unroll
    for (int e = 0; e < NE; ++e) {
      float4 wv = *reinterpret_cast<const float4*>(gw + e * HID + q * 256 + lane * 4);
      acc[e] += v.x * wv.x + v.y * wv.y + v.z * wv.z + v.w * wv.w;
    }
  }
#pragma unroll
  for (int e = 0; e < NE; ++e) {
#pragma unroll
    for (int off = 32; off > 0; off >>= 1) acc[e] += __shfl_xor(acc[e], off);
  }
  if (lane == 0) {
    float v0 = -1e30f; int i0 = 0;
#pragma unroll
    for (int e = 0; e < NE; ++e) if (acc[e] > v0) { v0 = acc[e]; i0 = e; }
    float v1 = -1e30f; int i1 = 0;
#pragma unroll
    for (int e = 0; e < NE; ++e) if (e != i0 && acc[e] > v1) { v1 = acc[e]; i1 = e; }
    float e1 = __expf(v1 - v0);
    float s = 1.f + e1;
    topi[gwave * 2] = i0; topi[gwave * 2 + 1] = i1;
    topw[gwave * 2] = 1.f / s; topw[gwave * 2 + 1] = e1 / s;
  }
}

// ---------- deterministic ballot-rank scatter: hist -> scan -> scatter ----------
__global__ __launch_bounds__(256) void hist_kernel(const int* __restrict__ topi,
                                                   int* __restrict__ bcnt)
{
  int tid = threadIdx.x, blk = blockIdx.x;
  int t = blk * 256 + tid;
  int e0 = topi[t * 2], e1 = topi[t * 2 + 1];
  int w = tid >> 6, lane = tid & 63;
  __shared__ int wcnt[4][NE];
#pragma unroll
  for (int e = 0; e < NE; ++e) {
    unsigned long long m0 = __ballot(e0 == e);
    unsigned long long m1 = __ballot(e1 == e);
    if (lane == 0) wcnt[w][e] = __popcll(m0) + __popcll(m1);
  }
  __syncthreads();
  if (tid < NE) {
    int s = 0;
#pragma unroll
    for (int w2 = 0; w2 < 4; ++w2) s += wcnt[w2][tid];
    bcnt[blk * NE + tid] = s;
  }
}

__global__ void scan2_kernel(const int* __restrict__ bcnt, int* __restrict__ offs,
                             int* __restrict__ tile_e, int* __restrict__ tile_m,
                             int* __restrict__ ntile, int* __restrict__ gbase)
{
  __shared__ int cnts[NE];
  __shared__ int soffs[NE];
  int tid = threadIdx.x;
  if (tid < NE) {
    int s = 0;
#pragma unroll
    for (int b = 0; b < 32; ++b) s += bcnt[b * NE + tid];
    cnts[tid] = s;
  }
  __syncthreads();
  if (tid == 0) {
    int o = 0, tt = 0;
    for (int e = 0; e < NE; ++e) {
      offs[e] = o; soffs[e] = o;
      int c = cnts[e];
      for (int m = 0; m < c; m += 256) { tile_e[tt] = e; tile_m[tt] = m; ++tt; }
      o += c;
    }
    offs[NE] = o;
    *ntile = tt;
  }
  __syncthreads();
  if (tid < 32 * NE) {
    int b = tid >> 3, e = tid & 7;
    int g = soffs[e];
    for (int b2 = 0; b2 < b; ++b2) g += bcnt[b2 * NE + e];
    gbase[b * NE + e] = g;
  }
}

__global__ __launch_bounds__(256) void scatter2_kernel(
    const int* __restrict__ topi, const float* __restrict__ topw,
    const int* __restrict__ gbase,
    int* __restrict__ toklist, float* __restrict__ wlist, int* __restrict__ pos)
{
  int tid = threadIdx.x, blk = blockIdx.x;
  int t = blk * 256 + tid;
  int e0 = topi[t * 2], e1 = topi[t * 2 + 1];
  float w0 = topw[t * 2], w1 = topw[t * 2 + 1];
  int w = tid >> 6, lane = tid & 63;
  unsigned long long lt = (1ull << lane) - 1ull;
  unsigned long long le = lt | (1ull << lane);
  __shared__ int wcnt[4][NE];
  __shared__ int wbase[4][NE];
  int r0 = 0, r1 = 0;
#pragma unroll
  for (int e = 0; e < NE; ++e) {
    unsigned long long m0 = __ballot(e0 == e);
    unsigned long long m1 = __ballot(e1 == e);
    if (lane == 0) wcnt[w][e] = __popcll(m0) + __popcll(m1);
    if (e0 == e) r0 = __popcll(m0 & lt) + __popcll(m1 & lt);
    if (e1 == e) r1 = __popcll(m0 & le) + __popcll(m1 & lt);
  }
  __syncthreads();
  if (tid < 4 * NE) {
    int w2 = tid >> 3, e = tid & 7;
    int b = gbase[blk * NE + e];
    for (int w3 = 0; w3 < w2; ++w3) b += wcnt[w3][e];
    wbase[w2][e] = b;
  }
  __syncthreads();
  int P0 = wbase[w][e0] + r0;
  int P1 = wbase[w][e1] + r1;
  toklist[P0] = t; wlist[P0] = w0; pos[t * 2] = P0;
  toklist[P1] = t; wlist[P1] = w1; pos[t * 2 + 1] = P1;
}

// ---------------- fp32 -> bf16 convert, W1 and W2 in one launch ----------------
__global__ __launch_bounds__(256) void cvtw_kernel(
    const float* __restrict__ W1, const float* __restrict__ W2,
    unsigned short* __restrict__ w1b, unsigned short* __restrict__ w2b, int n8)
{
  int half = gridDim.x >> 1;
  const float* src = (blockIdx.x < half) ? W1 : W2;
  unsigned short* dst = (blockIdx.x < half) ? w1b : w2b;
  int b0 = (blockIdx.x < half) ? blockIdx.x : blockIdx.x - half;
  int stride = half * 256;
  for (int i = b0 * 256 + threadIdx.x; i < n8; i += stride) {
    const float4* s = reinterpret_cast<const float4*>(src) + (size_t)i * 2;
    float4 a = s[0], b = s[1];
    ushort8v u;
    u[0] = f2b(a.x); u[1] = f2b(a.y); u[2] = f2b(a.z); u[3] = f2b(a.w);
    u[4] = f2b(b.x); u[5] = f2b(b.y); u[6] = f2b(b.z); u[7] = f2b(b.w);
    reinterpret_cast<ushort8v*>(dst)[i] = u;
  }
}

// ====== GEMM kernels (R13-proven): 256M x 128N tile, BK=32, 3-slot LDS ring
// (72 KB -> 2 blocks/CU), 8 waves (4M x 2N), wave tile 64x64. Pipeline:
//   { stage(s+2); WAITV(3) [s+1 landed]; s_barrier; MFMA(s) [frags in regs];
//     ds_read frags(s+1) }
// XCD-chunked flat grids: each XCD owns 9 consecutive tiles x all n-tiles.

// GEMM1: h = gelu(x @ W1[e]^T + b1[e]) -> bf16
__global__ __launch_bounds__(512, 4) void gemm1_kernel(
    const unsigned short* __restrict__ xb, const unsigned short* __restrict__ w1b,
    const float* __restrict__ b1,
    const int* __restrict__ toklist, const int* __restrict__ offs,
    const int* __restrict__ tile_e, const int* __restrict__ tile_m,
    const int* __restrict__ ntile,
    unsigned short* __restrict__ hb)
{
  const int h = blockIdx.x;            // 0..2303 = 8 xcd * (9 tiles * 32 n)
  const int xcd = h & 7;
  const int j = h >> 3;                // 0..287
  const int t = 9 * xcd + j % 9;
  const int n0 = (j / 9) * 128;        // 0..31 n-tiles
  if (t >= *ntile) return;
  const int e = tile_e[t];
  const int m0 = tile_m[t];
  const int base = offs[e];
  const int cnt = offs[e + 1] - base;

  __shared__ __align__(16) unsigned short As[3][256 * 32];  // 48 KB
  __shared__ __align__(16) unsigned short Bs[3][128 * 32];  // 24 KB

  const int tid = threadIdx.x;         // 0..511
  const int lane = tid & 63;
  const int w = tid >> 6;
  const int wr = w >> 1, wc = w & 1;   // 4M x 2N waves; per-wave out 64x64

  const int r0 = tid >> 2;             // 0..127
  const int sl = tid & 3;
  const int scg = sl ^ ((r0 >> 1) & 3);
  const unsigned short* gA[2];
  const unsigned short* gB;
#pragma unroll
  for (int g = 0; g < 2; ++g) {
    int row = g * 128 + r0;
    int mrow = m0 + row; if (mrow >= cnt) mrow = cnt - 1;
    int tk = toklist[base + mrow];
    gA[g] = xb + (size_t)tk * HID + scg * 8;
  }
  gB = w1b + ((size_t)e * INTER_ + n0 + r0) * HID + scg * 8;

  int raq[4], rbq[4];
#pragma unroll
  for (int i = 0; i < 4; ++i) {
    int rA = wr * 64 + i * 16 + (lane & 15);
    raq[i] = rA * 32 + (((lane >> 4) ^ ((rA >> 1) & 3)) * 8);
    int rB = wc * 64 + i * 16 + (lane & 15);
    rbq[i] = rB * 32 + (((lane >> 4) ^ ((rB >> 1) & 3)) * 8);
  }

  f32x4 acc[4][4];
#pragma unroll
  for (int i = 0; i < 4; ++i)
#pragma unroll
    for (int j2 = 0; j2 < 4; ++j2) acc[i][j2] = (f32x4){0.f, 0.f, 0.f, 0.f};

  bf16x8 afr[4], bfr[4];

  auto stage = [&](int slot, int s) {
    const int kof = s * 32;
    GLD_LDS(gA[0] + kof, &As[slot][tid * 8]);
    GLD_LDS(gA[1] + kof, &As[slot][4096 + tid * 8]);
    GLD_LDS(gB + kof,    &Bs[slot][tid * 8]);
  };
  auto load_frags = [&](int slot) {
    const unsigned short* Ab = &As[slot][0];
    const unsigned short* Bb = &Bs[slot][0];
#pragma unroll
    for (int j2 = 0; j2 < 4; ++j2) bfr[j2] = *reinterpret_cast<const bf16x8*>(Bb + rbq[j2]);
#pragma unroll
    for (int i = 0; i < 4; ++i) afr[i] = *reinterpret_cast<const bf16x8*>(Ab + raq[i]);
  };
  auto mfma_step = [&]() {
#pragma unroll
    for (int i = 0; i < 4; ++i)
#pragma unroll
      for (int j2 = 0; j2 < 4; ++j2)
        acc[i][j2] = __builtin_amdgcn_mfma_f32_16x16x32_bf16(afr[i], bfr[j2], acc[i][j2], 0, 0, 0);
  };

  const int NS = HID / 32;   // 32
  stage(0, 0); stage(1, 1);
  WAITV(3);
  __builtin_amdgcn_s_barrier();
  load_frags(0);
#pragma unroll 3
  for (int s = 0; s < NS - 2; ++s) {
    stage((s + 2) % 3, s + 2);
    WAITV(3);
    __builtin_amdgcn_s_barrier();
    mfma_step();
    load_frags((s + 1) % 3);
  }
  WAITV(0);
  __builtin_amdgcn_s_barrier();
  mfma_step();
  load_frags((NS - 1) % 3);
  mfma_step();

  float bias[4];
  const int colb = n0 + wc * 64 + (lane & 15);
#pragma unroll
  for (int j2 = 0; j2 < 4; ++j2) bias[j2] = b1[(size_t)e * INTER_ + colb + j2 * 16];
#pragma unroll
  for (int i = 0; i < 4; ++i) {
    int mbase = m0 + wr * 64 + i * 16 + (lane >> 4) * 4;
#pragma unroll
    for (int r = 0; r < 4; ++r) {
      int m = mbase + r;
      if (m < cnt) {
        unsigned short* hrow = hb + (size_t)(base + m) * INTER_ + colb;
#pragma unroll
        for (int j2 = 0; j2 < 4; ++j2)
          hrow[j2 * 16] = f2b(gelu_f(acc[i][j2][r] + bias[j2]));
      }
    }
  }
}

// GEMM2: P = h @ W2[e]^T — full K=4096 (no split), bf16 partials.
// 576 blocks = 2.25 rounds at 2/CU (same quantization as split's 1152/1024);
// halves part traffic vs split-K=2.
__global__ __launch_bounds__(512, 4) void gemm2_kernel(
    const unsigned short* __restrict__ hb, const unsigned short* __restrict__ w2b,
    const int* __restrict__ offs,
    const int* __restrict__ tile_e, const int* __restrict__ tile_m,
    const int* __restrict__ ntile,
    unsigned short* __restrict__ part)
{
  const int h = blockIdx.x;
  const int xcd = h & 7;
  const int j = h >> 3;            // 0..71
  const int t = 9 * xcd + j % 9;
  const int nb = j / 9;            // 0..7
  if (t >= *ntile) return;
  const int e = tile_e[t];
  const int m0 = tile_m[t];
  const int base = offs[e];
  const int cnt = offs[e + 1] - base;
  const int n0 = nb * 128;

  __shared__ __align__(16) unsigned short As[3][256 * 32];
  __shared__ __align__(16) unsigned short Bs[3][128 * 32];

  const int tid = threadIdx.x;
  const int lane = tid & 63;
  const int w = tid >> 6;
  const int wr = w >> 1, wc = w & 1;

  const int r0 = tid >> 2;
  const int sl = tid & 3;
  const int scg = sl ^ ((r0 >> 1) & 3);
  const unsigned short* gA[2];
  const unsigned short* gB;
#pragma unroll
  for (int g = 0; g < 2; ++g) {
    int row = g * 128 + r0;
    int mrow = m0 + row; if (mrow >= cnt) mrow = cnt - 1;
    gA[g] = hb + (size_t)(base + mrow) * INTER_ + scg * 8;
  }
  gB = w2b + ((size_t)e * HID + n0 + r0) * INTER_ + scg * 8;

  int raq[4], rbq[4];
#pragma unroll
  for (int i = 0; i < 4; ++i) {
    int rA = wr * 64 + i * 16 + (lane & 15);
    raq[i] = rA * 32 + (((lane >> 4) ^ ((rA >> 1) & 3)) * 8);
    int rB = wc * 64 + i * 16 + (lane & 15);
    rbq[i] = rB * 32 + (((lane >> 4) ^ ((rB >> 1) & 3)) * 8);
  }

  f32x4 acc[4][4];
#pragma unroll
  for (int i = 0; i < 4; ++i)
#pragma unroll
    for (int j2 = 0; j2 < 4; ++j2) acc[i][j2] = (f32x4){0.f, 0.f, 0.f, 0.f};

  bf16x8 afr[4], bfr[4];

  auto stage = [&](int slot, int s) {
    const int kof = s * 32;
    GLD_LDS(gA[0] + kof, &As[slot][tid * 8]);
    GLD_LDS(gA[1] + kof, &As[slot][4096 + tid * 8]);
    GLD_LDS(gB + kof,    &Bs[slot][tid * 8]);
  };
  auto load_frags = [&](int slot) {
    const unsigned short* Ab = &As[slot][0];
    const unsigned short* Bb = &Bs[slot][0];
#pragma unroll
    for (int j2 = 0; j2 < 4; ++j2) bfr[j2] = *reinterpret_cast<const bf16x8*>(Bb + rbq[j2]);
#pragma unroll
    for (int i = 0; i < 4; ++i) afr[i] = *reinterpret_cast<const bf16x8*>(Ab + raq[i]);
  };
  auto mfma_step = [&]() {
#pragma unroll
    for (int i = 0; i < 4; ++i)
#pragma unroll
      for (int j2 = 0; j2 < 4; ++j2)
        acc[i][j2] = __builtin_amdgcn_mfma_f32_16x16x32_bf16(afr[i], bfr[j2], acc[i][j2], 0, 0, 0);
  };

  const int NS = INTER_ / 32;   // 128
  stage(0, 0); stage(1, 1);
  WAITV(3);
  __builtin_amdgcn_s_barrier();
  load_frags(0);
#pragma unroll 3
  for (int s = 0; s < NS - 2; ++s) {
    stage((s + 2) % 3, s + 2);
    WAITV(3);
    __builtin_amdgcn_s_barrier();
    mfma_step();
    load_frags((s + 1) % 3);
  }
  WAITV(0);
  __builtin_amdgcn_s_barrier();
  mfma_step();
  load_frags((NS - 1) % 3);
  mfma_step();

  const int colb = n0 + wc * 64 + (lane & 15);
#pragma unroll
  for (int i = 0; i < 4; ++i) {
    int mbase = m0 + wr * 64 + i * 16 + (lane >> 4) * 4;
#pragma unroll
    for (int r = 0; r < 4; ++r) {
      int m = mbase + r;
      if (m < cnt) {
        unsigned short* prow = part + (size_t)(base + m) * HID + colb;
#pragma unroll
        for (int j2 = 0; j2 < 4; ++j2)
          prow[j2 * 16] = f2b(acc[i][j2][r]);
      }
    }
  }
}

// ---------- combine: out[t] = sum_k w_k * (P[pos_k] + b2[e_k]) ----------
__global__ __launch_bounds__(256) void combine_kernel(
    const unsigned short* __restrict__ part, const float* __restrict__ b2,
    const int* __restrict__ topi, const float* __restrict__ topw,
    const int* __restrict__ pos, float* __restrict__ out)
{
  int t = blockIdx.x * 4 + (threadIdx.x >> 6);
  int lane = threadIdx.x & 63;
  int c0 = lane * 16;
  float o[16];
#pragma unroll
  for (int c = 0; c < 16; ++c) o[c] = 0.f;
#pragma unroll
  for (int k = 0; k < 2; ++k) {
    int p = pos[t * 2 + k];
    int e = topi[t * 2 + k];
    float wk = topw[t * 2 + k];
    const unsigned short* rp = part + (size_t)p * HID + c0;
    const float* bb = b2 + (size_t)e * HID + c0;
#pragma unroll
    for (int v = 0; v < 2; ++v) {
      ushort8v a = *reinterpret_cast<const ushort8v*>(rp + v * 8);
      float4 bb0 = *reinterpret_cast<const float4*>(bb + v * 8);
      float4 bb1 = *reinterpret_cast<const float4*>(bb + v * 8 + 4);
      o[v * 8 + 0] += wk * (b2f(a[0]) + bb0.x);
      o[v * 8 + 1] += wk * (b2f(a[1]) + bb0.y);
      o[v * 8 + 2] += wk * (b2f(a[2]) + bb0.z);
      o[v * 8 + 3] += wk * (b2f(a[3]) + bb0.w);
      o[v * 8 + 4] += wk * (b2f(a[4]) + bb1.x);
      o[v * 8 + 5] += wk * (b2f(a[5]) + bb1.y);
      o[v * 8 + 6] += wk * (b2f(a[6]) + bb1.z);
      o[v * 8 + 7] += wk * (b2f(a[7]) + bb1.w);
    }
  }
  float4* op = reinterpret_cast<float4*>(out + (size_t)t * HID + c0);
#pragma unroll
  for (int v = 0; v < 4; ++v)
    op[v] = make_float4(o[v * 4], o[v * 4 + 1], o[v * 4 + 2], o[v * 4 + 3]);
}

extern "C" void kernel_launch(void* const* d_in, const int* in_sizes, int n_in,
                              void* d_out, int out_size, void* d_ws, size_t ws_size,
                              hipStream_t stream) {
  const float* x  = (const float*)d_in[0];
  const float* gw = (const float*)d_in[1];
  const float* W1 = (const float*)d_in[2];
  const float* b1 = (const float*)d_in[3];
  const float* W2 = (const float*)d_in[4];
  const float* b2 = (const float*)d_in[5];
  float* out = (float*)d_out;

  char* ws = (char*)d_ws;
  size_t off = 0;
  auto alloc = [&](size_t bytes) -> void* {
    void* p = ws + off;
    off += (bytes + 255) & ~(size_t)255;
    return p;
  };
  unsigned short* hb   = (unsigned short*)alloc((size_t)NPAIR * INTER_ * 2);     // 134.2 MB
  unsigned short* xb   = (unsigned short*)alloc((size_t)NTOK * HID * 2);         //  16.8 MB
  unsigned short* w1b  = (unsigned short*)alloc((size_t)NE * INTER_ * HID * 2);  //  67.1 MB
  unsigned short* w2b  = (unsigned short*)alloc((size_t)NE * HID * INTER_ * 2);  //  67.1 MB
  unsigned short* part = (unsigned short*)alloc((size_t)NPAIR * HID * 2);        //  33.6 MB
  int*   toklist = (int*)alloc(NPAIR * 4);
  float* wlist   = (float*)alloc(NPAIR * 4);
  int*   topi    = (int*)alloc(NTOK * 2 * 4);
  float* topw    = (float*)alloc(NTOK * 2 * 4);
  int*   pos     = (int*)alloc(NTOK * 2 * 4);
  int*   bcnt    = (int*)alloc(32 * NE * 4);
  int*   gbase   = (int*)alloc(32 * NE * 4);
  int*   offs    = (int*)alloc(64);
  int*   tile_e  = (int*)alloc(MAXT * 4);
  int*   tile_m  = (int*)alloc(MAXT * 4);
  int*   ntile   = (int*)alloc(64);

  gate_kernel<<<NTOK / 4, 256, 0, stream>>>(x, gw, topi, topw, xb);
  hist_kernel<<<32, 256, 0, stream>>>(topi, bcnt);
  scan2_kernel<<<1, 256, 0, stream>>>(bcnt, offs, tile_e, tile_m, ntile, gbase);
  scatter2_kernel<<<32, 256, 0, stream>>>(topi, topw, gbase, toklist, wlist, pos);
  cvtw_kernel<<<4096, 256, 0, stream>>>(W1, W2, w1b, w2b, NE * INTER_ * HID / 8);
  gemm1_kernel<<<dim3(8 * 9 * 32), 512, 0, stream>>>(
      xb, w1b, b1, toklist, offs, tile_e, tile_m, ntile, hb);
  gemm2_kernel<<<dim3(8 * MAXT), 512, 0, stream>>>(
      hb, w2b, offs, tile_e, tile_m, ntile, part);
  combine_kernel<<<NTOK / 4, 256, 0, stream>>>(part, b2, topi, topw, pos, out);
}

// Round 16
// 486.126 us; speedup vs baseline: 1.0663x; 1.0177x over previous
//
#include <hip/hip_runtime.h>
#include <hip/hip_bf16.h>
#include <stdint.h>

#define HID 1024
#define INTER_ 4096
#define NE 8
#define NTOK 8192
#define NPAIR (NTOK * 2)
#define MAXT 72   // sum ceil(cnt_e/256) <= 16384/256 + 8

using f32x4 = __attribute__((ext_vector_type(4))) float;
using bf16x8 = __attribute__((ext_vector_type(8))) __bf16;
using ushort8v = __attribute__((ext_vector_type(8))) unsigned short;

__device__ __forceinline__ unsigned short f2b(float f) {
  unsigned int u = __float_as_uint(f);
  u += 0x7fffu + ((u >> 16) & 1u);
  return (unsigned short)(u >> 16);
}
__device__ __forceinline__ float b2f(unsigned short u) {
  return __uint_as_float((unsigned int)u << 16);
}

// branch-free gelu: A&S 7.1.26 erf (abs err 1.5e-7)
__device__ __forceinline__ float gelu_f(float v) {
  float z = fabsf(v) * 0.70710678118654752f;
  float t = __builtin_amdgcn_rcpf(1.f + 0.3275911f * z);
  float p = t * (0.254829592f +
            t * (-0.284496736f +
            t * (1.421413741f +
            t * (-1.453152027f + t * 1.061405429f))));
  float er = 1.f - p * __expf(-z * z);
  er = copysignf(er, v);
  return 0.5f * v * (1.f + er);
}

#define GLD_LDS(gp, lp)                                                        \
  __builtin_amdgcn_global_load_lds(                                            \
      (const __attribute__((address_space(1))) unsigned int*)(const void*)(gp),\
      (__attribute__((address_space(3))) unsigned int*)(void*)(lp), 16, 0, 0)

#define WAITV(N) asm volatile("s_waitcnt vmcnt(" #N ")" ::: "memory")

// ---------------- fp32 -> bf16 convert, W1 and W2 in one launch ----------------
// Launched FIRST so w1b/w2b are L3-hot for the GEMMs and cvtw's 402 MB stream
// does not evict xb between gate and gemm1.
__global__ __launch_bounds__(256) void cvtw_kernel(
    const float* __restrict__ W1, const float* __restrict__ W2,
    unsigned short* __restrict__ w1b, unsigned short* __restrict__ w2b, int n8)
{
  int half = gridDim.x >> 1;
  const float* src = (blockIdx.x < half) ? W1 : W2;
  unsigned short* dst = (blockIdx.x < half) ? w1b : w2b;
  int b0 = (blockIdx.x < half) ? blockIdx.x : blockIdx.x - half;
  int stride = half * 256;
  for (int i = b0 * 256 + threadIdx.x; i < n8; i += stride) {
    const float4* s = reinterpret_cast<const float4*>(src) + (size_t)i * 2;
    float4 a = s[0], b = s[1];
    ushort8v u;
    u[0] = f2b(a.x); u[1] = f2b(a.y); u[2] = f2b(a.z); u[3] = f2b(a.w);
    u[4] = f2b(b.x); u[5] = f2b(b.y); u[6] = f2b(b.z); u[7] = f2b(b.w);
    reinterpret_cast<ushort8v*>(dst)[i] = u;
  }
}

// ---------------- gating: one wave per token, fp32; also emits xb ----------------
__global__ __launch_bounds__(256) void gate_kernel(
    const float* __restrict__ x, const float* __restrict__ gw,
    int* __restrict__ topi, float* __restrict__ topw,
    unsigned short* __restrict__ xb)
{
  int gwave = (blockIdx.x * 256 + threadIdx.x) >> 6;
  int lane = threadIdx.x & 63;
  if (gwave >= NTOK) return;
  const float* xr = x + (size_t)gwave * HID;
  unsigned short* xo = xb + (size_t)gwave * HID;
  float acc[NE];
#pragma unroll
  for (int e = 0; e < NE; ++e) acc[e] = 0.f;
#pragma unroll
  for (int q = 0; q < 4; ++q) {
    float4 v = *reinterpret_cast<const float4*>(xr + q * 256 + lane * 4);
    ushort4 uv;
    uv.x = f2b(v.x); uv.y = f2b(v.y); uv.z = f2b(v.z); uv.w = f2b(v.w);
    *reinterpret_cast<ushort4*>(xo + q * 256 + lane * 4) = uv;
#pragma unroll
    for (int e = 0; e < NE; ++e) {
      float4 wv = *reinterpret_cast<const float4*>(gw + e * HID + q * 256 + lane * 4);
      acc[e] += v.x * wv.x + v.y * wv.y + v.z * wv.z + v.w * wv.w;
    }
  }
#pragma unroll
  for (int e = 0; e < NE; ++e) {
#pragma unroll
    for (int off = 32; off > 0; off >>= 1) acc[e] += __shfl_xor(acc[e], off);
  }
  if (lane == 0) {
    float v0 = -1e30f; int i0 = 0;
#pragma unroll
    for (int e = 0; e < NE; ++e) if (acc[e] > v0) { v0 = acc[e]; i0 = e; }
    float v1 = -1e30f; int i1 = 0;
#pragma unroll
    for (int e = 0; e < NE; ++e) if (e != i0 && acc[e] > v1) { v1 = acc[e]; i1 = e; }
    float e1 = __expf(v1 - v0);
    float s = 1.f + e1;
    topi[gwave * 2] = i0; topi[gwave * 2 + 1] = i1;
    topw[gwave * 2] = 1.f / s; topw[gwave * 2 + 1] = e1 / s;
  }
}

// ---------- deterministic ballot-rank scatter: hist -> scan -> scatter ----------
__global__ __launch_bounds__(256) void hist_kernel(const int* __restrict__ topi,
                                                   int* __restrict__ bcnt)
{
  int tid = threadIdx.x, blk = blockIdx.x;
  int t = blk * 256 + tid;
  int e0 = topi[t * 2], e1 = topi[t * 2 + 1];
  int w = tid >> 6, lane = tid & 63;
  __shared__ int wcnt[4][NE];
#pragma unroll
  for (int e = 0; e < NE; ++e) {
    unsigned long long m0 = __ballot(e0 == e);
    unsigned long long m1 = __ballot(e1 == e);
    if (lane == 0) wcnt[w][e] = __popcll(m0) + __popcll(m1);
  }
  __syncthreads();
  if (tid < NE) {
    int s = 0;
#pragma unroll
    for (int w2 = 0; w2 < 4; ++w2) s += wcnt[w2][tid];
    bcnt[blk * NE + tid] = s;
  }
}

__global__ void scan2_kernel(const int* __restrict__ bcnt, int* __restrict__ offs,
                             int* __restrict__ tile_e, int* __restrict__ tile_m,
                             int* __restrict__ ntile, int* __restrict__ gbase)
{
  __shared__ int cnts[NE];
  __shared__ int soffs[NE];
  int tid = threadIdx.x;
  if (tid < NE) {
    int s = 0;
#pragma unroll
    for (int b = 0; b < 32; ++b) s += bcnt[b * NE + tid];
    cnts[tid] = s;
  }
  __syncthreads();
  if (tid == 0) {
    int o = 0, tt = 0;
    for (int e = 0; e < NE; ++e) {
      offs[e] = o; soffs[e] = o;
      int c = cnts[e];
      for (int m = 0; m < c; m += 256) { tile_e[tt] = e; tile_m[tt] = m; ++tt; }
      o += c;
    }
    offs[NE] = o;
    *ntile = tt;
  }
  __syncthreads();
  if (tid < 32 * NE) {
    int b = tid >> 3, e = tid & 7;
    int g = soffs[e];
    for (int b2 = 0; b2 < b; ++b2) g += bcnt[b2 * NE + e];
    gbase[b * NE + e] = g;
  }
}

__global__ __launch_bounds__(256) void scatter2_kernel(
    const int* __restrict__ topi, const float* __restrict__ topw,
    const int* __restrict__ gbase,
    int* __restrict__ toklist, float* __restrict__ wlist, int* __restrict__ pos)
{
  int tid = threadIdx.x, blk = blockIdx.x;
  int t = blk * 256 + tid;
  int e0 = topi[t * 2], e1 = topi[t * 2 + 1];
  float w0 = topw[t * 2], w1 = topw[t * 2 + 1];
  int w = tid >> 6, lane = tid & 63;
  unsigned long long lt = (1ull << lane) - 1ull;
  unsigned long long le = lt | (1ull << lane);
  __shared__ int wcnt[4][NE];
  __shared__ int wbase[4][NE];
  int r0 = 0, r1 = 0;
#pragma unroll
  for (int e = 0; e < NE; ++e) {
    unsigned long long m0 = __ballot(e0 == e);
    unsigned long long m1 = __ballot(e1 == e);
    if (lane == 0) wcnt[w][e] = __popcll(m0) + __popcll(m1);
    if (e0 == e) r0 = __popcll(m0 & lt) + __popcll(m1 & lt);
    if (e1 == e) r1 = __popcll(m0 & le) + __popcll(m1 & lt);
  }
  __syncthreads();
  if (tid < 4 * NE) {
    int w2 = tid >> 3, e = tid & 7;
    int b = gbase[blk * NE + e];
    for (int w3 = 0; w3 < w2; ++w3) b += wcnt[w3][e];
    wbase[w2][e] = b;
  }
  __syncthreads();
  int P0 = wbase[w][e0] + r0;
  int P1 = wbase[w][e1] + r1;
  toklist[P0] = t; wlist[P0] = w0; pos[t * 2] = P0;
  toklist[P1] = t; wlist[P1] = w1; pos[t * 2 + 1] = P1;
}

// ====== GEMM kernels (R13-proven): 256M x 128N tile, BK=32, 3-slot LDS ring
// (72 KB -> 2 blocks/CU), 8 waves (4M x 2N), wave tile 64x64. Pipeline:
//   { stage(s+2); WAITV(3) [s+1 landed]; s_barrier; MFMA(s) [frags in regs];
//     ds_read frags(s+1) }
// XCD-chunked flat grids: each XCD owns 9 consecutive tiles x all n-tiles.

// GEMM1: h = gelu(x @ W1[e]^T + b1[e]) -> bf16
__global__ __launch_bounds__(512, 4) void gemm1_kernel(
    const unsigned short* __restrict__ xb, const unsigned short* __restrict__ w1b,
    const float* __restrict__ b1,
    const int* __restrict__ toklist, const int* __restrict__ offs,
    const int* __restrict__ tile_e, const int* __restrict__ tile_m,
    const int* __restrict__ ntile,
    unsigned short* __restrict__ hb)
{
  const int h = blockIdx.x;            // 0..2303 = 8 xcd * (9 tiles * 32 n)
  const int xcd = h & 7;
  const int j = h >> 3;                // 0..287
  const int t = 9 * xcd + j % 9;
  const int n0 = (j / 9) * 128;        // 0..31 n-tiles
  if (t >= *ntile) return;
  const int e = tile_e[t];
  const int m0 = tile_m[t];
  const int base = offs[e];
  const int cnt = offs[e + 1] - base;

  __shared__ __align__(16) unsigned short As[3][256 * 32];  // 48 KB
  __shared__ __align__(16) unsigned short Bs[3][128 * 32];  // 24 KB

  const int tid = threadIdx.x;         // 0..511
  const int lane = tid & 63;
  const int w = tid >> 6;
  const int wr = w >> 1, wc = w & 1;   // 4M x 2N waves; per-wave out 64x64

  const int r0 = tid >> 2;             // 0..127
  const int sl = tid & 3;
  const int scg = sl ^ ((r0 >> 1) & 3);
  const unsigned short* gA[2];
  const unsigned short* gB;
#pragma unroll
  for (int g = 0; g < 2; ++g) {
    int row = g * 128 + r0;
    int mrow = m0 + row; if (mrow >= cnt) mrow = cnt - 1;
    int tk = toklist[base + mrow];
    gA[g] = xb + (size_t)tk * HID + scg * 8;
  }
  gB = w1b + ((size_t)e * INTER_ + n0 + r0) * HID + scg * 8;

  int raq[4], rbq[4];
#pragma unroll
  for (int i = 0; i < 4; ++i) {
    int rA = wr * 64 + i * 16 + (lane & 15);
    raq[i] = rA * 32 + (((lane >> 4) ^ ((rA >> 1) & 3)) * 8);
    int rB = wc * 64 + i * 16 + (lane & 15);
    rbq[i] = rB * 32 + (((lane >> 4) ^ ((rB >> 1) & 3)) * 8);
  }

  f32x4 acc[4][4];
#pragma unroll
  for (int i = 0; i < 4; ++i)
#pragma unroll
    for (int j2 = 0; j2 < 4; ++j2) acc[i][j2] = (f32x4){0.f, 0.f, 0.f, 0.f};

  bf16x8 afr[4], bfr[4];

  auto stage = [&](int slot, int s) {
    const int kof = s * 32;
    GLD_LDS(gA[0] + kof, &As[slot][tid * 8]);
    GLD_LDS(gA[1] + kof, &As[slot][4096 + tid * 8]);
    GLD_LDS(gB + kof,    &Bs[slot][tid * 8]);
  };
  auto load_frags = [&](int slot) {
    const unsigned short* Ab = &As[slot][0];
    const unsigned short* Bb = &Bs[slot][0];
#pragma unroll
    for (int j2 = 0; j2 < 4; ++j2) bfr[j2] = *reinterpret_cast<const bf16x8*>(Bb + rbq[j2]);
#pragma unroll
    for (int i = 0; i < 4; ++i) afr[i] = *reinterpret_cast<const bf16x8*>(Ab + raq[i]);
  };
  auto mfma_step = [&]() {
#pragma unroll
    for (int i = 0; i < 4; ++i)
#pragma unroll
      for (int j2 = 0; j2 < 4; ++j2)
        acc[i][j2] = __builtin_amdgcn_mfma_f32_16x16x32_bf16(afr[i], bfr[j2], acc[i][j2], 0, 0, 0);
  };

  const int NS = HID / 32;   // 32
  stage(0, 0); stage(1, 1);
  WAITV(3);
  __builtin_amdgcn_s_barrier();
  load_frags(0);
#pragma unroll 3
  for (int s = 0; s < NS - 2; ++s) {
    stage((s + 2) % 3, s + 2);
    WAITV(3);
    __builtin_amdgcn_s_barrier();
    mfma_step();
    load_frags((s + 1) % 3);
  }
  WAITV(0);
  __builtin_amdgcn_s_barrier();
  mfma_step();
  load_frags((NS - 1) % 3);
  mfma_step();

  float bias[4];
  const int colb = n0 + wc * 64 + (lane & 15);
#pragma unroll
  for (int j2 = 0; j2 < 4; ++j2) bias[j2] = b1[(size_t)e * INTER_ + colb + j2 * 16];
#pragma unroll
  for (int i = 0; i < 4; ++i) {
    int mbase = m0 + wr * 64 + i * 16 + (lane >> 4) * 4;
#pragma unroll
    for (int r = 0; r < 4; ++r) {
      int m = mbase + r;
      if (m < cnt) {
        unsigned short* hrow = hb + (size_t)(base + m) * INTER_ + colb;
#pragma unroll
        for (int j2 = 0; j2 < 4; ++j2)
          hrow[j2 * 16] = f2b(gelu_f(acc[i][j2][r] + bias[j2]));
      }
    }
  }
}

// GEMM2: P[z] = h @ W2[e]^T (split-K=2, bf16 partials), XCD-chunked flat grid.
__global__ __launch_bounds__(512, 4) void gemm2_kernel(
    const unsigned short* __restrict__ hb, const unsigned short* __restrict__ w2b,
    const int* __restrict__ offs,
    const int* __restrict__ tile_e, const int* __restrict__ tile_m,
    const int* __restrict__ ntile,
    unsigned short* __restrict__ part)
{
  const int h = blockIdx.x;
  const int xcd = h & 7;
  const int j = h >> 3;            // 0..71
  const int t = 9 * xcd + j % 9;
  const int nb = j / 9;            // 0..7
  if (t >= *ntile) return;
  const int e = tile_e[t];
  const int m0 = tile_m[t];
  const int base = offs[e];
  const int cnt = offs[e + 1] - base;
  const int n0 = nb * 128;
  const int kbase = blockIdx.z * (INTER_ / 2);

  __shared__ __align__(16) unsigned short As[3][256 * 32];
  __shared__ __align__(16) unsigned short Bs[3][128 * 32];

  const int tid = threadIdx.x;
  const int lane = tid & 63;
  const int w = tid >> 6;
  const int wr = w >> 1, wc = w & 1;

  const int r0 = tid >> 2;
  const int sl = tid & 3;
  const int scg = sl ^ ((r0 >> 1) & 3);
  const unsigned short* gA[2];
  const unsigned short* gB;
#pragma unroll
  for (int g = 0; g < 2; ++g) {
    int row = g * 128 + r0;
    int mrow = m0 + row; if (mrow >= cnt) mrow = cnt - 1;
    gA[g] = hb + (size_t)(base + mrow) * INTER_ + kbase + scg * 8;
  }
  gB = w2b + ((size_t)e * HID + n0 + r0) * INTER_ + kbase + scg * 8;

  int raq[4], rbq[4];
#pragma unroll
  for (int i = 0; i < 4; ++i) {
    int rA = wr * 64 + i * 16 + (lane & 15);
    raq[i] = rA * 32 + (((lane >> 4) ^ ((rA >> 1) & 3)) * 8);
    int rB = wc * 64 + i * 16 + (lane & 15);
    rbq[i] = rB * 32 + (((lane >> 4) ^ ((rB >> 1) & 3)) * 8);
  }

  f32x4 acc[4][4];
#pragma unroll
  for (int i = 0; i < 4; ++i)
#pragma unroll
    for (int j2 = 0; j2 < 4; ++j2) acc[i][j2] = (f32x4){0.f, 0.f, 0.f, 0.f};

  bf16x8 afr[4], bfr[4];

  auto stage = [&](int slot, int s) {
    const int kof = s * 32;
    GLD_LDS(gA[0] + kof, &As[slot][tid * 8]);
    GLD_LDS(gA[1] + kof, &As[slot][4096 + tid * 8]);
    GLD_LDS(gB + kof,    &Bs[slot][tid * 8]);
  };
  auto load_frags = [&](int slot) {
    const unsigned short* Ab = &As[slot][0];
    const unsigned short* Bb = &Bs[slot][0];
#pragma unroll
    for (int j2 = 0; j2 < 4; ++j2) bfr[j2] = *reinterpret_cast<const bf16x8*>(Bb + rbq[j2]);
#pragma unroll
    for (int i = 0; i < 4; ++i) afr[i] = *reinterpret_cast<const bf16x8*>(Ab + raq[i]);
  };
  auto mfma_step = [&]() {
#pragma unroll
    for (int i = 0; i < 4; ++i)
#pragma unroll
      for (int j2 = 0; j2 < 4; ++j2)
        acc[i][j2] = __builtin_amdgcn_mfma_f32_16x16x32_bf16(afr[i], bfr[j2], acc[i][j2], 0, 0, 0);
  };

  const int NS = (INTER_ / 2) / 32;   // 64
  stage(0, 0); stage(1, 1);
  WAITV(3);
  __builtin_amdgcn_s_barrier();
  load_frags(0);
#pragma unroll 3
  for (int s = 0; s < NS - 2; ++s) {
    stage((s + 2) % 3, s + 2);
    WAITV(3);
    __builtin_amdgcn_s_barrier();
    mfma_step();
    load_frags((s + 1) % 3);
  }
  WAITV(0);
  __builtin_amdgcn_s_barrier();
  mfma_step();
  load_frags((NS - 1) % 3);
  mfma_step();

  const int colb = n0 + wc * 64 + (lane & 15);
  unsigned short* pbase = part + (size_t)blockIdx.z * NPAIR * HID;
#pragma unroll
  for (int i = 0; i < 4; ++i) {
    int mbase = m0 + wr * 64 + i * 16 + (lane >> 4) * 4;
#pragma unroll
    for (int r = 0; r < 4; ++r) {
      int m = mbase + r;
      if (m < cnt) {
        unsigned short* prow = pbase + (size_t)(base + m) * HID + colb;
#pragma unroll
        for (int j2 = 0; j2 < 4; ++j2)
          prow[j2 * 16] = f2b(acc[i][j2][r]);
      }
    }
  }
}

// ---------- combine: out[t] = sum_k w_k * (P0[pos_k] + P1[pos_k] + b2[e_k]) ----------
__global__ __launch_bounds__(256) void combine_kernel(
    const unsigned short* __restrict__ part, const float* __restrict__ b2,
    const int* __restrict__ topi, const float* __restrict__ topw,
    const int* __restrict__ pos, float* __restrict__ out)
{
  int t = blockIdx.x * 4 + (threadIdx.x >> 6);
  int lane = threadIdx.x & 63;
  int c0 = lane * 16;
  float o[16];
#pragma unroll
  for (int c = 0; c < 16; ++c) o[c] = 0.f;
#pragma unroll
  for (int k = 0; k < 2; ++k) {
    int p = pos[t * 2 + k];
    int e = topi[t * 2 + k];
    float wk = topw[t * 2 + k];
    const unsigned short* rp0 = part + (size_t)p * HID + c0;
    const unsigned short* rp1 = part + ((size_t)NPAIR + p) * HID + c0;
    const float* bb = b2 + (size_t)e * HID + c0;
#pragma unroll
    for (int v = 0; v < 2; ++v) {
      ushort8v a = *reinterpret_cast<const ushort8v*>(rp0 + v * 8);
      ushort8v b = *reinterpret_cast<const ushort8v*>(rp1 + v * 8);
      float4 bb0 = *reinterpret_cast<const float4*>(bb + v * 8);
      float4 bb1 = *reinterpret_cast<const float4*>(bb + v * 8 + 4);
      o[v * 8 + 0] += wk * (b2f(a[0]) + b2f(b[0]) + bb0.x);
      o[v * 8 + 1] += wk * (b2f(a[1]) + b2f(b[1]) + bb0.y);
      o[v * 8 + 2] += wk * (b2f(a[2]) + b2f(b[2]) + bb0.z);
      o[v * 8 + 3] += wk * (b2f(a[3]) + b2f(b[3]) + bb0.w);
      o[v * 8 + 4] += wk * (b2f(a[4]) + b2f(b[4]) + bb1.x);
      o[v * 8 + 5] += wk * (b2f(a[5]) + b2f(b[5]) + bb1.y);
      o[v * 8 + 6] += wk * (b2f(a[6]) + b2f(b[6]) + bb1.z);
      o[v * 8 + 7] += wk * (b2f(a[7]) + b2f(b[7]) + bb1.w);
    }
  }
  float4* op = reinterpret_cast<float4*>(out + (size_t)t * HID + c0);
#pragma unroll
  for (int v = 0; v < 4; ++v)
    op[v] = make_float4(o[v * 4], o[v * 4 + 1], o[v * 4 + 2], o[v * 4 + 3]);
}

extern "C" void kernel_launch(void* const* d_in, const int* in_sizes, int n_in,
                              void* d_out, int out_size, void* d_ws, size_t ws_size,
                              hipStream_t stream) {
  const float* x  = (const float*)d_in[0];
  const float* gw = (const float*)d_in[1];
  const float* W1 = (const float*)d_in[2];
  const float* b1 = (const float*)d_in[3];
  const float* W2 = (const float*)d_in[4];
  const float* b2 = (const float*)d_in[5];
  float* out = (float*)d_out;

  char* ws = (char*)d_ws;
  size_t off = 0;
  auto alloc = [&](size_t bytes) -> void* {
    void* p = ws + off;
    off += (bytes + 255) & ~(size_t)255;
    return p;
  };
  unsigned short* hb   = (unsigned short*)alloc((size_t)NPAIR * INTER_ * 2);     // 134.2 MB
  unsigned short* xb   = (unsigned short*)alloc((size_t)NTOK * HID * 2);         //  16.8 MB
  unsigned short* w1b  = (unsigned short*)alloc((size_t)NE * INTER_ * HID * 2);  //  67.1 MB
  unsigned short* w2b  = (unsigned short*)alloc((size_t)NE * HID * INTER_ * 2);  //  67.1 MB
  unsigned short* part = (unsigned short*)alloc((size_t)2 * NPAIR * HID * 2);    //  67.1 MB
  int*   toklist = (int*)alloc(NPAIR * 4);
  float* wlist   = (float*)alloc(NPAIR * 4);
  int*   topi    = (int*)alloc(NTOK * 2 * 4);
  float* topw    = (float*)alloc(NTOK * 2 * 4);
  int*   pos     = (int*)alloc(NTOK * 2 * 4);
  int*   bcnt    = (int*)alloc(32 * NE * 4);
  int*   gbase   = (int*)alloc(32 * NE * 4);
  int*   offs    = (int*)alloc(64);
  int*   tile_e  = (int*)alloc(MAXT * 4);
  int*   tile_m  = (int*)alloc(MAXT * 4);
  int*   ntile   = (int*)alloc(64);

  // cvtw FIRST: its 402 MB stream runs before gate writes xb, so xb/w1b are
  // L3-hot when gemm1 starts (previously cvtw evicted them in between).
  cvtw_kernel<<<4096, 256, 0, stream>>>(W1, W2, w1b, w2b, NE * INTER_ * HID / 8);
  gate_kernel<<<NTOK / 4, 256, 0, stream>>>(x, gw, topi, topw, xb);
  hist_kernel<<<32, 256, 0, stream>>>(topi, bcnt);
  scan2_kernel<<<1, 256, 0, stream>>>(bcnt, offs, tile_e, tile_m, ntile, gbase);
  scatter2_kernel<<<32, 256, 0, stream>>>(topi, topw, gbase, toklist, wlist, pos);
  gemm1_kernel<<<dim3(8 * 9 * 32), 512, 0, stream>>>(
      xb, w1b, b1, toklist, offs, tile_e, tile_m, ntile, hb);
  gemm2_kernel<<<dim3(8 * MAXT, 1, 2), 512, 0, stream>>>(
      hb, w2b, offs, tile_e, tile_m, ntile, part);
  combine_kernel<<<NTOK / 4, 256, 0, stream>>>(part, b2, topi, topw, pos, out);
}